// Round 15
// baseline (94.560 us; speedup 1.0000x reference)
//
#include <hip/hip_runtime.h>
#include <cstdint>
#include <cstddef>

typedef __bf16 bf16;
typedef __attribute__((ext_vector_type(2))) __bf16 bf16x2;
typedef __attribute__((ext_vector_type(8))) __bf16 bf16x8;
typedef __attribute__((ext_vector_type(2))) float f32x2;
typedef __attribute__((ext_vector_type(4))) float f32x4;
typedef __attribute__((ext_vector_type(2))) _Float16 f16x2;

#define EPS_C 1e-4f

// light barrier: LDS visibility only, vmem loads stay in flight (no vmcnt drain)
#define BAR_LDS() do { asm volatile("s_waitcnt lgkmcnt(0)" ::: "memory"); \
                       __builtin_amdgcn_s_barrier(); } while (0)

// ================= K0: weights prep + zero page =================
// Whg: reduced in_proj hi bf16, COLUMN-PERMUTED (each 48-col group = 16 delta +
// 16 Bmean + 16 Cmean), chunk-major [k/32][n_new][k%32] = MFMA B-fragment order.
// Wlg: lo-part of the 64 delta rows only, [k/32][d][k%32].
// Wob: out_proj bf16 [dm][i].
__global__ __launch_bounds__(256) void k0_prep(const float* __restrict__ Wi,
    const float* __restrict__ Wo, bf16* __restrict__ Whg, bf16* __restrict__ Wlg,
    bf16* __restrict__ Wob, float* __restrict__ zpg)
{
    int idx = blockIdx.x * 256 + threadIdx.x;
    if (idx < 196608) {
        int nn = idx >> 10, k = idx & 1023;
        int wn = nn / 48, s = nn - wn * 48;
        if (s < 16) {
            int d = wn * 16 + s;
            float w = Wi[d * 1024 + k];
            bf16 h = (bf16)w;
            Whg[(k >> 5) * 6144 + nn * 32 + (k & 31)] = h;
            Wlg[(k >> 5) * 2048 + d * 32 + (k & 31)] = (bf16)(w - (float)h);
        } else if (s < 32) {
            int i = wn * 16 + (s - 16);
            float w = 0.5f * (Wi[(64 + 2 * i) * 1024 + k] + Wi[(65 + 2 * i) * 1024 + k]);
            Whg[(k >> 5) * 6144 + nn * 32 + (k & 31)] = (bf16)w;
        } else {
            int i = wn * 16 + (s - 32);
            float w = 0.5f * (Wi[(192 + 2 * i) * 1024 + k] + Wi[(193 + 2 * i) * 1024 + k]);
            Whg[(k >> 5) * 6144 + nn * 32 + (k & 31)] = (bf16)w;
        }
    } else if (idx < 262144) {
        int j = idx - 196608;
        Wob[j] = (bf16)Wo[j];
    } else {
        int j = idx - 262144;
        if (j < 1024) zpg[j] = 0.f;
    }
}

// ================= K1: conv + MFMA in_proj (delta 3-pass, B/C 2-pass) + SSM + scan =================
// t-tile 128, 512 threads (2 t-halves x 4 n-quarters), grid 256 = 1 block/CU.
// QUAD-ROW conv staging: 7 shared taps / 4 rows / 2 ch -> x VMEM 2.38x -> 1.67x ideal.
// xc tiles pitch 80 B; one light barrier/chunk; W direct global->reg (wt-pair L1 dedup).
__global__ __launch_bounds__(512) void k1_convproj(
    const float* __restrict__ x, const float* __restrict__ conv_w,
    const float* __restrict__ conv_b, const float* __restrict__ in_proj_b,
    const float* __restrict__ A_log,
    const bf16* __restrict__ Whg, const bf16* __restrict__ Wlg,
    const float* __restrict__ zpg,
    f16x2* __restrict__ YZp,
    float* __restrict__ Psum, float* __restrict__ Ssum)
{
    __shared__ char smem[61440];
    // xh buf p @ p*10240 | xl buf p @ 20480+p*10240 (each 10240 = 128 rows x 80 B)
    // cwT[4][1024] f32 @40960 (16384) | cbl[1024] f32 @57344 (4096)
    // epilogue overlay: res[64][196] f32 @0 (50176) | part[2][8][64] @50176 (4096)

    const int tid  = threadIdx.x;
    const int lane = tid & 63;
    const int wv   = tid >> 6;               // 0..7
    const int wt   = wv >> 2, wn = wv & 3;
    const int fr   = lane & 15, fs = lane >> 4;
    const int b    = blockIdx.x >> 5;
    const int tc   = blockIdx.x & 31;
    const int t0   = tc * 128;
    const int rot  = (blockIdx.x * 5) & 31;

    // quad-row conv mapping: thread -> (row-quad tp 0..31, 2-ch slot cs2 0..15)
    const int tp  = tid >> 4, cs2 = tid & 15;
    const int r0  = tp * 4;
    const int gt0 = t0 + r0;
    const bool zr3 = (gt0 + 3 == 4095);      // only row == 3 (mod 4) can be 4095

    int aoff[4];
#pragma unroll
    for (int mi = 0; mi < 4; ++mi) {
        int r = wt * 64 + mi * 16 + fr;
        aoff[mi] = r * 80 + fs * 16;
    }

    // 7 tap pointers (rows gt0-1 .. gt0+5; OOB -> zero page)
    const float* rp[7];
#pragma unroll
    for (int dt = 0; dt < 7; ++dt) {
        int g = gt0 - 1 + dt;
        rp[dt] = (g >= 0 && g < 4096) ? (x + ((size_t)b * 4096 + g) * 1024 + cs2 * 2)
                                      : (zpg + cs2 * 2);
    }

    // W fragment offsets within a chunk (wt-pair waves read identical lines)
    const size_t wfo  = (size_t)(wn * 48 + fr) * 32 + fs * 8;   // hi (192 cols)
    const size_t wfol = (size_t)(wn * 16 + fr) * 32 + fs * 8;   // delta-lo (64 cols)

    // ---- preload conv tables to LDS (tap-major) ----
    {
        float* cwT = (float*)(smem + 40960);
        float* cbl = (float*)(smem + 57344);
        for (int p = tid; p < 1024; p += 512) {
            f32x4 w4 = *(const f32x4*)&conv_w[p * 4];
            cwT[p]        = w4.x;
            cwT[1024 + p] = w4.y;
            cwT[2048 + p] = w4.z;
            cwT[3072 + p] = w4.w;
        }
        if (tid < 256) ((f32x4*)cbl)[tid] = ((const f32x4*)conv_b)[tid];
    }

    f32x2  xr[7];
    bf16x8 wfh[3], wfl;
    f32x4  acc[4][3] = {};

    auto L = [&](int c) { return (c + rot) & 31; };

    auto fetch_x = [&](int lc) {
#pragma unroll
        for (int dt = 0; dt < 7; ++dt)
            xr[dt] = *(const f32x2*)(rp[dt] + lc * 32);
    };
    auto fetch_w = [&](int lc) {
        const bf16* ph = Whg + (size_t)lc * 6144 + wfo;
#pragma unroll
        for (int ni = 0; ni < 3; ++ni)
            wfh[ni] = *(const bf16x8*)(ph + ni * 512);
        wfl = *(const bf16x8*)(Wlg + (size_t)lc * 2048 + wfol);
    };
    auto conv = [&](int lc, int p) {         // conv logical chunk lc from xr -> LDS buf p
        char* xh = smem + p * 10240;
        char* xl = smem + 20480 + p * 10240;
        const float* cwT = (const float*)(smem + 40960);
        const float* cbl = (const float*)(smem + 57344);
        const int ch0 = lc * 32 + cs2 * 2;
        f32x2 w0 = *(const f32x2*)&cwT[ch0];
        f32x2 w1 = *(const f32x2*)&cwT[1024 + ch0];
        f32x2 w2 = *(const f32x2*)&cwT[2048 + ch0];
        f32x2 w3 = *(const f32x2*)&cwT[3072 + ch0];
        f32x2 bb = *(const f32x2*)&cbl[ch0];
#pragma unroll
        for (int r = 0; r < 4; ++r) {
            float v0 = bb.x, v1 = bb.y;
            v0 = fmaf(w0.x, xr[r + 0].x, v0);
            v0 = fmaf(w1.x, xr[r + 1].x, v0);
            v0 = fmaf(w2.x, xr[r + 2].x, v0);
            v0 = fmaf(w3.x, xr[r + 3].x, v0);
            v1 = fmaf(w0.y, xr[r + 0].y, v1);
            v1 = fmaf(w1.y, xr[r + 1].y, v1);
            v1 = fmaf(w2.y, xr[r + 2].y, v1);
            v1 = fmaf(w3.y, xr[r + 3].y, v1);
            if (r == 3 && zr3) { v0 = 0.f; v1 = 0.f; }
            bf16 h0 = (bf16)v0, h1 = (bf16)v1;
            bf16x2 hp, lp;
            hp[0] = h0; hp[1] = h1;
            lp[0] = (bf16)(v0 - (float)h0);
            lp[1] = (bf16)(v1 - (float)h1);
            int off = (r0 + r) * 80 + cs2 * 4;
            *(bf16x2*)(xh + off) = hp;
            *(bf16x2*)(xl + off) = lp;
        }
    };

    // ---- prologue ----
    fetch_x(L(0));
    fetch_w(L(0));
    __syncthreads();                         // conv tables visible
    conv(L(0), 0);
    fetch_x(L(1));
    __syncthreads();                         // buf0 visible

    auto body = [&](int c, int par) {
        const char* xh = smem + par * 10240;
        const char* xl = smem + 20480 + par * 10240;
        bf16x8 ah[4], al[4];
#pragma unroll
        for (int mi = 0; mi < 4; ++mi) {
            ah[mi] = *(const bf16x8*)(xh + aoff[mi]);
            al[mi] = *(const bf16x8*)(xl + aoff[mi]);
        }
        __builtin_amdgcn_s_setprio(1);
#pragma unroll
        for (int ni = 0; ni < 3; ++ni) {
            bf16x8 bh = wfh[ni];
#pragma unroll
            for (int mi = 0; mi < 4; ++mi)
                acc[mi][ni] = __builtin_amdgcn_mfma_f32_16x16x32_bf16(ah[mi], bh, acc[mi][ni], 0, 0, 0);
#pragma unroll
            for (int mi = 0; mi < 4; ++mi)
                acc[mi][ni] = __builtin_amdgcn_mfma_f32_16x16x32_bf16(al[mi], bh, acc[mi][ni], 0, 0, 0);
        }
#pragma unroll
        for (int mi = 0; mi < 4; ++mi)
            acc[mi][0] = __builtin_amdgcn_mfma_f32_16x16x32_bf16(ah[mi], wfl, acc[mi][0], 0, 0, 0);
        __builtin_amdgcn_s_setprio(0);
        if (c + 1 < 32) {
            fetch_w(L(c + 1));               // in flight across barrier
            conv(L(c + 1), par ^ 1);         // xr = x(L(c+1)), write other buffer
            if (c + 2 < 32) fetch_x(L(c + 2));
        }
        BAR_LDS();                           // NO vmcnt drain
    };

#pragma unroll 1
    for (int cc = 0; cc < 32; cc += 2) {
        body(cc,     0);
        body(cc + 1, 1);
    }

    // ---- epilogue: two 64-row passes; res[64][196] overlay; SSM + chunk-local scan ----
    float* res  = (float*)smem;
    float* part = (float*)(smem + 50176);    // [2][8][64]
    const int i  = lane;
    const int tg = tid >> 6;                 // 0..7: 8 rows each within the 64-row half
    const float A  = -expf(A_log[i]);
    const float bd = in_proj_b[i];
    const float bB = 0.5f * (in_proj_b[64 + 2 * i] + in_proj_b[65 + 2 * i]);
    const float bC = 0.5f * (in_proj_b[192 + 2 * i] + in_proj_b[193 + 2 * i]);
    const bool tiny = fabsf(A) < EPS_C;
    const int dcol = (i >> 4) * 48 + (i & 15);   // un-permute columns

#pragma unroll 1
    for (int hh = 0; hh < 2; ++hh) {
        __syncthreads();                     // prior res/part consumers done
        if (wt == hh) {
#pragma unroll
            for (int mi = 0; mi < 4; ++mi)
#pragma unroll
                for (int ni = 0; ni < 3; ++ni) {
                    int col = wn * 48 + ni * 16 + fr;
#pragma unroll
                    for (int r = 0; r < 4; ++r)
                        res[(mi * 16 + fs * 4 + r) * 196 + col] = acc[mi][ni][r];
                }
        }
        __syncthreads();
        float av[8], bv[8], cv[8];
#pragma unroll
        for (int r = 0; r < 8; ++r) {
            int t = tg * 8 + r;
            float d  = res[t * 196 + dcol] + bd;
            float Bm = res[t * 196 + dcol + 16] + bB;
            float Cm = res[t * 196 + dcol + 32] + bC;
            float delta = (d > 20.f) ? d : log1pf(expf(d));
            float dA = delta * A;
            float abar = expf(dA);
            float sc = tiny ? (1.f + dA * 0.5f + dA * dA * (1.f / 6.f)) : ((abar - 1.f) / A);
            av[r] = abar; bv[r] = sc * Bm; cv[r] = Cm;
        }
        float P = 1.f, S = 0.f;
#pragma unroll
        for (int r = 0; r < 8; ++r) { S = fmaf(av[r], S, bv[r]); P *= av[r]; }
        part[tg * 64 + i] = P;
        part[512 + tg * 64 + i] = S;
        __syncthreads();
        float h = 0.f, pp = 1.f;
#pragma unroll
        for (int g = 0; g < 7; ++g)
            if (g < tg) {
                float Pg = part[g * 64 + i], Sg = part[512 + g * 64 + i];
                h = fmaf(Pg, h, Sg);
                pp *= Pg;
            }
        size_t ob = ((size_t)b * 4096 + t0 + hh * 64 + tg * 8) * 64 + i;
#pragma unroll
        for (int r = 0; r < 8; ++r) {
            h  = fmaf(av[r], h, bv[r]);      // 64-row-chunk-local state
            pp *= av[r];                     // 64-row-chunk-local prefix product
            f16x2 yz;
            yz[0] = (_Float16)(cv[r] * h);
            yz[1] = (_Float16)(cv[r] * pp);
            YZp[ob + (size_t)r * 64] = yz;
        }
        if (tg == 7) {
            size_t o = ((size_t)b * 64 + tc * 2 + hh) * 64 + i;
            Psum[o] = pp;
            Ssum[o] = h;
        }
    }
}

// ================= K2: serial carry combine across 64 chunks =================
__global__ __launch_bounds__(64) void k2_scan2(const float* __restrict__ Psum,
    const float* __restrict__ Ssum, float* __restrict__ Carry)
{
    int b = blockIdx.x, i = threadIdx.x;
    float Pv[64], Sv[64];
#pragma unroll
    for (int c = 0; c < 64; ++c) {
        size_t o = ((size_t)(b * 64) + c) * 64 + i;
        Pv[c] = Psum[o]; Sv[c] = Ssum[o];
    }
    float h = 0.f;
#pragma unroll
    for (int c = 0; c < 64; ++c) {
        size_t o = ((size_t)(b * 64) + c) * 64 + i;
        Carry[o] = h;
        h = fmaf(Pv[c], h, Sv[c]);
    }
}

// ================= K3: y = Y + Z*carry (f16 packed), fused out_proj MFMA =================
// 512 threads (8 waves). Block = 64-t chunk; wave: 64t x 128n.
__global__ __launch_bounds__(512) void k3_scan_out(
    const f16x2* __restrict__ YZp, const float* __restrict__ Carry,
    const bf16* __restrict__ Wob, const float* __restrict__ bo,
    float* __restrict__ out)
{
    __shared__ char sm3[8192];               // [64 t][64 i] bf16, swizzled

    const int tid  = threadIdx.x;
    const int lane = tid & 63;
    const int wv   = tid >> 6;
    const int b    = blockIdx.x >> 6;
    const int ch   = blockIdx.x & 63;
    const int t0   = ch * 64;

    const int i = lane, tg = wv;
    float cr = Carry[((size_t)(b * 64) + ch) * 64 + i];
    size_t base = ((size_t)(b * 4096) + t0 + tg * 8) * 64 + i;
#pragma unroll
    for (int r = 0; r < 8; ++r) {
        f16x2 yz = YZp[base + (size_t)r * 64];
        float y = (float)yz[0] + (float)yz[1] * cr;
        int t = tg * 8 + r;
        int off = t * 128 + ((((i >> 3) ^ (t & 7)) & 7) << 4) + (i & 7) * 2;
        *(bf16*)(sm3 + off) = (bf16)y;
    }
    __syncthreads();

    const int fr = lane & 15, fs = lane >> 4;
    bf16x8 afr[4][2];
#pragma unroll
    for (int mi = 0; mi < 4; ++mi)
#pragma unroll
        for (int ks = 0; ks < 2; ++ks) {
            int row = mi * 16 + fr;
            int slot = ks * 4 + fs;
            int off = row * 128 + (((slot ^ (row & 7)) & 7) << 4);
            afr[mi][ks] = *(const bf16x8*)(sm3 + off);
        }
    const int n0 = wv * 128;
#pragma unroll
    for (int ni = 0; ni < 8; ++ni) {
        int col = n0 + ni * 16 + fr;
        bf16x8 b0 = *(const bf16x8*)(Wob + (size_t)col * 64 + fs * 8);
        bf16x8 b1 = *(const bf16x8*)(Wob + (size_t)col * 64 + 32 + fs * 8);
        float bias = bo[col];
#pragma unroll
        for (int mi = 0; mi < 4; ++mi) {
            f32x4 a = {};
            a = __builtin_amdgcn_mfma_f32_16x16x32_bf16(afr[mi][0], b0, a, 0, 0, 0);
            a = __builtin_amdgcn_mfma_f32_16x16x32_bf16(afr[mi][1], b1, a, 0, 0, 0);
#pragma unroll
            for (int r = 0; r < 4; ++r) {
                int t = mi * 16 + fs * 4 + r;
                out[((size_t)(b * 4096) + t0 + t) * 1024 + col] = a[r] + bias;
            }
        }
    }
}

extern "C" void kernel_launch(void* const* d_in, const int* in_sizes, int n_in,
                              void* d_out, int out_size, void* d_ws, size_t ws_size,
                              hipStream_t stream) {
    const float* x          = (const float*)d_in[0];
    const float* conv_w     = (const float*)d_in[1];
    const float* conv_b     = (const float*)d_in[2];
    const float* in_proj_w  = (const float*)d_in[3];
    const float* in_proj_b  = (const float*)d_in[4];
    const float* A_log      = (const float*)d_in[5];
    const float* out_proj_w = (const float*)d_in[6];
    const float* out_proj_b = (const float*)d_in[7];
    float* out = (float*)d_out;

    char* w = (char*)d_ws;
    bf16*  Whg  = (bf16*)w;                         // 393216
    bf16*  Wlg  = (bf16*)(w + 393216);              // 131072 -> 524288
    bf16*  Wob  = (bf16*)(w + 524288);              // 131072 -> 655360
    f16x2* YZp  = (f16x2*)(w + 655360);             // 8 MiB  -> 9043968
    float* Psum = (float*)(w + 9043968);            // 128 KiB -> 9175040
    float* Ssum = (float*)(w + 9175040);            // 128 KiB -> 9306112
    float* Carry= (float*)(w + 9306112);            // 128 KiB -> 9437184
    float* zpg  = (float*)(w + 9437184);            // 4 KiB zeroed

    hipLaunchKernelGGL(k0_prep,     dim3(1032), dim3(256), 0, stream,
                       in_proj_w, out_proj_w, Whg, Wlg, Wob, zpg);
    hipLaunchKernelGGL(k1_convproj, dim3(256),  dim3(512), 0, stream,
                       x, conv_w, conv_b, in_proj_b, A_log, Whg, Wlg, zpg,
                       YZp, Psum, Ssum);
    hipLaunchKernelGGL(k2_scan2,    dim3(8),    dim3(64),  0, stream, Psum, Ssum, Carry);
    hipLaunchKernelGGL(k3_scan_out, dim3(512),  dim3(512), 0, stream,
                       YZp, Carry, Wob, out_proj_b, out);
}

// Round 16
// 91.721 us; speedup vs baseline: 1.0309x; 1.0309x over previous
//
#include <hip/hip_runtime.h>
#include <cstdint>
#include <cstddef>

typedef __bf16 bf16;
typedef __attribute__((ext_vector_type(4))) __bf16 bf16x4;
typedef __attribute__((ext_vector_type(8))) __bf16 bf16x8;
typedef __attribute__((ext_vector_type(4))) float f32x4;
typedef __attribute__((ext_vector_type(2))) _Float16 f16x2;

#define EPS_C 1e-4f

// light barrier: LDS visibility only, vmem loads stay in flight (no vmcnt drain)
#define BAR_LDS() do { asm volatile("s_waitcnt lgkmcnt(0)" ::: "memory"); \
                       __builtin_amdgcn_s_barrier(); } while (0)

// ================= K0: weights prep + zero page =================
// Whg: reduced in_proj hi bf16, COLUMN-PERMUTED (each 48-col group = 16 delta +
// 16 Bmean + 16 Cmean), chunk-major [k/32][n_new][k%32] = MFMA B-fragment order.
// Wlg: lo-part of the 64 delta rows only, [k/32][d][k%32].
// Wob: out_proj bf16 [dm][i].
__global__ __launch_bounds__(256) void k0_prep(const float* __restrict__ Wi,
    const float* __restrict__ Wo, bf16* __restrict__ Whg, bf16* __restrict__ Wlg,
    bf16* __restrict__ Wob, float* __restrict__ zpg)
{
    int idx = blockIdx.x * 256 + threadIdx.x;
    if (idx < 196608) {
        int nn = idx >> 10, k = idx & 1023;
        int wn = nn / 48, s = nn - wn * 48;
        if (s < 16) {
            int d = wn * 16 + s;
            float w = Wi[d * 1024 + k];
            bf16 h = (bf16)w;
            Whg[(k >> 5) * 6144 + nn * 32 + (k & 31)] = h;
            Wlg[(k >> 5) * 2048 + d * 32 + (k & 31)] = (bf16)(w - (float)h);
        } else if (s < 32) {
            int i = wn * 16 + (s - 16);
            float w = 0.5f * (Wi[(64 + 2 * i) * 1024 + k] + Wi[(65 + 2 * i) * 1024 + k]);
            Whg[(k >> 5) * 6144 + nn * 32 + (k & 31)] = (bf16)w;
        } else {
            int i = wn * 16 + (s - 32);
            float w = 0.5f * (Wi[(192 + 2 * i) * 1024 + k] + Wi[(193 + 2 * i) * 1024 + k]);
            Whg[(k >> 5) * 6144 + nn * 32 + (k & 31)] = (bf16)w;
        }
    } else if (idx < 262144) {
        int j = idx - 196608;
        Wob[j] = (bf16)Wo[j];
    } else {
        int j = idx - 262144;
        if (j < 1024) zpg[j] = 0.f;
    }
}

// ================= K1: conv + MFMA in_proj (delta 3-pass, B/C 2-pass) + SSM + scan =================
// t-tile 128, 512 threads (2 t-halves x 4 n-quarters), grid 256 = 1 block/CU.
// RAW-X LDS STAGING: chunk's x (131 rows x 32 ch f32) staged once (1.02x redundancy,
// 16B requests); conv reads 5 taps from LDS. Raw pitch 144 B (aligned, bank-uniform).
// xc tiles pitch 80 B; one light barrier/chunk; W direct global->reg (wt-pair L1 dedup).
__global__ __launch_bounds__(512) void k1_convproj(
    const float* __restrict__ x, const float* __restrict__ conv_w,
    const float* __restrict__ conv_b, const float* __restrict__ in_proj_b,
    const float* __restrict__ A_log,
    const bf16* __restrict__ Whg, const bf16* __restrict__ Wlg,
    const float* __restrict__ zpg,
    f16x2* __restrict__ YZp,
    float* __restrict__ Psum, float* __restrict__ Ssum)
{
    __shared__ char smem[99328];
    // raw x f32 [131][144B] dbuf: raw0 @0 (18944), raw1 @18944      (ends 37888)
    // xh buf p @37888+p*10240 | xl buf p @58368+p*10240             (ends 78848)
    // cwT[4][1024] f32 @78848 (16384) | cbl[1024] f32 @95232 (4096) (ends 99328)
    // epilogue overlay: res[64][196] f32 @0 (50176) | part[2][8][64] @50176 (4096)

    const int tid  = threadIdx.x;
    const int lane = tid & 63;
    const int wv   = tid >> 6;               // 0..7
    const int wt   = wv >> 2, wn = wv & 3;
    const int fr   = lane & 15, fs = lane >> 4;
    const int b    = blockIdx.x >> 5;
    const int tc   = blockIdx.x & 31;
    const int t0   = tc * 128;
    const int rot  = (blockIdx.x * 5) & 31;

    // pair-row conv mapping: thread -> (t-pair tp 0..63, 4-ch quad cs 0..7)
    const int tp = tid >> 3, cs = tid & 7;
    const bool zrow1 = (t0 + tp * 2 + 1 == 4095);   // even rows can never be 4095
    const int woff0 = (tp * 2)     * 80 + cs * 8;   // xc pitch-80 (bank rotation)
    const int woff1 = (tp * 2 + 1) * 80 + cs * 8;
    const int rbase = tp * 2 * 144 + cs * 16;       // raw tap base (raw row = t+1)

    int aoff[4];
#pragma unroll
    for (int mi = 0; mi < 4; ++mi) {
        int r = wt * 64 + mi * 16 + fr;
        aoff[mi] = r * 80 + fs * 16;
    }

    // raw staging: slots s = tid, tid+512, (tid<24: tid+1024); slot -> (row s>>3, quad s&7)
    const float* sp[3];
    int soff[3];
#pragma unroll
    for (int j = 0; j < 3; ++j) {
        int s = tid + j * 512;
        int row = s >> 3, q = s & 7;
        int g = t0 - 1 + row;                // raw row r holds global row t0-1+r
        bool ok = (s < 1048) && (g >= 0) && (g < 4096);
        sp[j]   = ok ? (x + ((size_t)b * 4096 + g) * 1024 + q * 4) : (zpg + q * 4);
        soff[j] = row * 144 + q * 16;
    }
    const bool s2ok = (tid < 24);

    // W fragment offsets within a chunk (wt-pair waves read identical lines)
    const size_t wfo  = (size_t)(wn * 48 + fr) * 32 + fs * 8;   // hi (192 cols)
    const size_t wfol = (size_t)(wn * 16 + fr) * 32 + fs * 8;   // delta-lo (64 cols)

    // ---- preload conv tables to LDS (tap-major) ----
    {
        float* cwT = (float*)(smem + 78848);
        float* cbl = (float*)(smem + 95232);
        for (int p = tid; p < 1024; p += 512) {
            f32x4 w4 = *(const f32x4*)&conv_w[p * 4];
            cwT[p]        = w4.x;
            cwT[1024 + p] = w4.y;
            cwT[2048 + p] = w4.z;
            cwT[3072 + p] = w4.w;
        }
        if (tid < 256) ((f32x4*)cbl)[tid] = ((const f32x4*)conv_b)[tid];
    }

    f32x4  xs[3];
    bf16x8 wfh[3], wfl;
    f32x4  acc[4][3] = {};

    auto L = [&](int c) { return (c + rot) & 31; };

    auto fetch_x = [&](int lc) {
        xs[0] = *(const f32x4*)(sp[0] + lc * 32);
        xs[1] = *(const f32x4*)(sp[1] + lc * 32);
        if (s2ok) xs[2] = *(const f32x4*)(sp[2] + lc * 32);
    };
    auto raw_write = [&](int c) {            // xs -> raw buf[c&1]
        char* rb = smem + (c & 1) * 18944;
        *(f32x4*)(rb + soff[0]) = xs[0];
        *(f32x4*)(rb + soff[1]) = xs[1];
        if (s2ok) *(f32x4*)(rb + soff[2]) = xs[2];
    };
    auto fetch_w = [&](int lc) {
        const bf16* ph = Whg + (size_t)lc * 6144 + wfo;
#pragma unroll
        for (int ni = 0; ni < 3; ++ni)
            wfh[ni] = *(const bf16x8*)(ph + ni * 512);
        wfl = *(const bf16x8*)(Wlg + (size_t)lc * 2048 + wfol);
    };
    auto conv = [&](int c, int lc) {         // raw buf[c&1] -> xc buf[c&1]
        const char* rb = smem + (c & 1) * 18944;
        char* xh = smem + 37888 + (c & 1) * 10240;
        char* xl = smem + 58368 + (c & 1) * 10240;
        const float* cwT = (const float*)(smem + 78848);
        const float* cbl = (const float*)(smem + 95232);
        f32x4 xt[5];
#pragma unroll
        for (int dt = 0; dt < 5; ++dt)
            xt[dt] = *(const f32x4*)(rb + rbase + dt * 144);
        const int ch0 = lc * 32 + cs * 4;
        f32x4 w0 = *(const f32x4*)&cwT[ch0];
        f32x4 w1 = *(const f32x4*)&cwT[1024 + ch0];
        f32x4 w2 = *(const f32x4*)&cwT[2048 + ch0];
        f32x4 w3 = *(const f32x4*)&cwT[3072 + ch0];
        f32x4 bb = *(const f32x4*)&cbl[ch0];
        bf16x4 hi0, lo0, hi1, lo1;
#pragma unroll
        for (int j = 0; j < 4; ++j) {
            float v0 = bb[j];
            v0 = fmaf(w0[j], xt[0][j], v0);
            v0 = fmaf(w1[j], xt[1][j], v0);
            v0 = fmaf(w2[j], xt[2][j], v0);
            v0 = fmaf(w3[j], xt[3][j], v0);
            float v1 = bb[j];
            v1 = fmaf(w0[j], xt[1][j], v1);
            v1 = fmaf(w1[j], xt[2][j], v1);
            v1 = fmaf(w2[j], xt[3][j], v1);
            v1 = fmaf(w3[j], xt[4][j], v1);
            v1 = zrow1 ? 0.f : v1;
            bf16 h0 = (bf16)v0, h1 = (bf16)v1;
            hi0[j] = h0; lo0[j] = (bf16)(v0 - (float)h0);
            hi1[j] = h1; lo1[j] = (bf16)(v1 - (float)h1);
        }
        *(bf16x4*)(xh + woff0) = hi0;
        *(bf16x4*)(xh + woff1) = hi1;
        *(bf16x4*)(xl + woff0) = lo0;
        *(bf16x4*)(xl + woff1) = lo1;
    };

    // ---- prologue ----
    fetch_x(L(0));
    fetch_w(L(0));
    raw_write(0);                            // waits chunk-0 x loads
    fetch_x(L(1));
    __syncthreads();                         // tables + raw0 visible
    conv(0, L(0));                           // raw0 -> xc0
    raw_write(1);                            // raw1
    fetch_x(L(2));
    BAR_LDS();                               // xc0 + raw1 visible

    auto body = [&](int c, int par) {
        const char* xh = smem + 37888 + par * 10240;
        const char* xl = smem + 58368 + par * 10240;
        bf16x8 ah[4], al[4];
#pragma unroll
        for (int mi = 0; mi < 4; ++mi) {
            ah[mi] = *(const bf16x8*)(xh + aoff[mi]);
            al[mi] = *(const bf16x8*)(xl + aoff[mi]);
        }
        __builtin_amdgcn_s_setprio(1);
#pragma unroll
        for (int ni = 0; ni < 3; ++ni) {
            bf16x8 bh = wfh[ni];
#pragma unroll
            for (int mi = 0; mi < 4; ++mi)
                acc[mi][ni] = __builtin_amdgcn_mfma_f32_16x16x32_bf16(ah[mi], bh, acc[mi][ni], 0, 0, 0);
#pragma unroll
            for (int mi = 0; mi < 4; ++mi)
                acc[mi][ni] = __builtin_amdgcn_mfma_f32_16x16x32_bf16(al[mi], bh, acc[mi][ni], 0, 0, 0);
        }
#pragma unroll
        for (int mi = 0; mi < 4; ++mi)
            acc[mi][0] = __builtin_amdgcn_mfma_f32_16x16x32_bf16(ah[mi], wfl, acc[mi][0], 0, 0, 0);
        __builtin_amdgcn_s_setprio(0);
        if (c + 1 < 32) {
            fetch_w(L(c + 1));               // in flight across barrier
            conv(c + 1, L(c + 1));           // raw[(c+1)&1] -> xc[(c+1)&1]
            if (c + 2 < 32) raw_write(c + 2);        // xs(c+2) -> raw[c&1] (read-done 1 barrier ago)
            if (c + 3 < 32) fetch_x(L(c + 3));       // next loads in flight
        }
        BAR_LDS();                           // NO vmcnt drain
    };

#pragma unroll 1
    for (int cc = 0; cc < 32; cc += 2) {
        body(cc,     0);
        body(cc + 1, 1);
    }

    // ---- epilogue: two 64-row passes; res[64][196] overlay; SSM + chunk-local scan ----
    float* res  = (float*)smem;
    float* part = (float*)(smem + 50176);    // [2][8][64]
    const int i  = lane;
    const int tg = tid >> 6;                 // 0..7: 8 rows each within the 64-row half
    const float A  = -expf(A_log[i]);
    const float bd = in_proj_b[i];
    const float bB = 0.5f * (in_proj_b[64 + 2 * i] + in_proj_b[65 + 2 * i]);
    const float bC = 0.5f * (in_proj_b[192 + 2 * i] + in_proj_b[193 + 2 * i]);
    const bool tiny = fabsf(A) < EPS_C;
    const int dcol = (i >> 4) * 48 + (i & 15);   // un-permute columns

#pragma unroll 1
    for (int hh = 0; hh < 2; ++hh) {
        __syncthreads();                     // prior res/part consumers done
        if (wt == hh) {
#pragma unroll
            for (int mi = 0; mi < 4; ++mi)
#pragma unroll
                for (int ni = 0; ni < 3; ++ni) {
                    int col = wn * 48 + ni * 16 + fr;
#pragma unroll
                    for (int r = 0; r < 4; ++r)
                        res[(mi * 16 + fs * 4 + r) * 196 + col] = acc[mi][ni][r];
                }
        }
        __syncthreads();
        float av[8], bv[8], cv[8];
#pragma unroll
        for (int r = 0; r < 8; ++r) {
            int t = tg * 8 + r;
            float d  = res[t * 196 + dcol] + bd;
            float Bm = res[t * 196 + dcol + 16] + bB;
            float Cm = res[t * 196 + dcol + 32] + bC;
            float delta = (d > 20.f) ? d : log1pf(expf(d));
            float dA = delta * A;
            float abar = expf(dA);
            float sc = tiny ? (1.f + dA * 0.5f + dA * dA * (1.f / 6.f)) : ((abar - 1.f) / A);
            av[r] = abar; bv[r] = sc * Bm; cv[r] = Cm;
        }
        float P = 1.f, S = 0.f;
#pragma unroll
        for (int r = 0; r < 8; ++r) { S = fmaf(av[r], S, bv[r]); P *= av[r]; }
        part[tg * 64 + i] = P;
        part[512 + tg * 64 + i] = S;
        __syncthreads();
        float h = 0.f, pp = 1.f;
#pragma unroll
        for (int g = 0; g < 7; ++g)
            if (g < tg) {
                float Pg = part[g * 64 + i], Sg = part[512 + g * 64 + i];
                h = fmaf(Pg, h, Sg);
                pp *= Pg;
            }
        size_t ob = ((size_t)b * 4096 + t0 + hh * 64 + tg * 8) * 64 + i;
#pragma unroll
        for (int r = 0; r < 8; ++r) {
            h  = fmaf(av[r], h, bv[r]);      // 64-row-chunk-local state
            pp *= av[r];                     // 64-row-chunk-local prefix product
            f16x2 yz;
            yz[0] = (_Float16)(cv[r] * h);
            yz[1] = (_Float16)(cv[r] * pp);
            YZp[ob + (size_t)r * 64] = yz;
        }
        if (tg == 7) {
            size_t o = ((size_t)b * 64 + tc * 2 + hh) * 64 + i;
            Psum[o] = pp;
            Ssum[o] = h;
        }
    }
}

// ================= K2: serial carry combine across 64 chunks =================
__global__ __launch_bounds__(64) void k2_scan2(const float* __restrict__ Psum,
    const float* __restrict__ Ssum, float* __restrict__ Carry)
{
    int b = blockIdx.x, i = threadIdx.x;
    float Pv[64], Sv[64];
#pragma unroll
    for (int c = 0; c < 64; ++c) {
        size_t o = ((size_t)(b * 64) + c) * 64 + i;
        Pv[c] = Psum[o]; Sv[c] = Ssum[o];
    }
    float h = 0.f;
#pragma unroll
    for (int c = 0; c < 64; ++c) {
        size_t o = ((size_t)(b * 64) + c) * 64 + i;
        Carry[o] = h;
        h = fmaf(Pv[c], h, Sv[c]);
    }
}

// ================= K3: y = Y + Z*carry (f16 packed), fused out_proj MFMA =================
// 512 threads (8 waves). Block = 64-t chunk; wave: 64t x 128n.
__global__ __launch_bounds__(512) void k3_scan_out(
    const f16x2* __restrict__ YZp, const float* __restrict__ Carry,
    const bf16* __restrict__ Wob, const float* __restrict__ bo,
    float* __restrict__ out)
{
    __shared__ char sm3[8192];               // [64 t][64 i] bf16, swizzled

    const int tid  = threadIdx.x;
    const int lane = tid & 63;
    const int wv   = tid >> 6;
    const int b    = blockIdx.x >> 6;
    const int ch   = blockIdx.x & 63;
    const int t0   = ch * 64;

    const int i = lane, tg = wv;
    float cr = Carry[((size_t)(b * 64) + ch) * 64 + i];
    size_t base = ((size_t)(b * 4096) + t0 + tg * 8) * 64 + i;
#pragma unroll
    for (int r = 0; r < 8; ++r) {
        f16x2 yz = YZp[base + (size_t)r * 64];
        float y = (float)yz[0] + (float)yz[1] * cr;
        int t = tg * 8 + r;
        int off = t * 128 + ((((i >> 3) ^ (t & 7)) & 7) << 4) + (i & 7) * 2;
        *(bf16*)(sm3 + off) = (bf16)y;
    }
    __syncthreads();

    const int fr = lane & 15, fs = lane >> 4;
    bf16x8 afr[4][2];
#pragma unroll
    for (int mi = 0; mi < 4; ++mi)
#pragma unroll
        for (int ks = 0; ks < 2; ++ks) {
            int row = mi * 16 + fr;
            int slot = ks * 4 + fs;
            int off = row * 128 + (((slot ^ (row & 7)) & 7) << 4);
            afr[mi][ks] = *(const bf16x8*)(sm3 + off);
        }
    const int n0 = wv * 128;
#pragma unroll
    for (int ni = 0; ni < 8; ++ni) {
        int col = n0 + ni * 16 + fr;
        bf16x8 b0 = *(const bf16x8*)(Wob + (size_t)col * 64 + fs * 8);
        bf16x8 b1 = *(const bf16x8*)(Wob + (size_t)col * 64 + 32 + fs * 8);
        float bias = bo[col];
#pragma unroll
        for (int mi = 0; mi < 4; ++mi) {
            f32x4 a = {};
            a = __builtin_amdgcn_mfma_f32_16x16x32_bf16(afr[mi][0], b0, a, 0, 0, 0);
            a = __builtin_amdgcn_mfma_f32_16x16x32_bf16(afr[mi][1], b1, a, 0, 0, 0);
#pragma unroll
            for (int r = 0; r < 4; ++r) {
                int t = mi * 16 + fs * 4 + r;
                out[((size_t)(b * 4096) + t0 + t) * 1024 + col] = a[r] + bias;
            }
        }
    }
}

extern "C" void kernel_launch(void* const* d_in, const int* in_sizes, int n_in,
                              void* d_out, int out_size, void* d_ws, size_t ws_size,
                              hipStream_t stream) {
    const float* x          = (const float*)d_in[0];
    const float* conv_w     = (const float*)d_in[1];
    const float* conv_b     = (const float*)d_in[2];
    const float* in_proj_w  = (const float*)d_in[3];
    const float* in_proj_b  = (const float*)d_in[4];
    const float* A_log      = (const float*)d_in[5];
    const float* out_proj_w = (const float*)d_in[6];
    const float* out_proj_b = (const float*)d_in[7];
    float* out = (float*)d_out;

    char* w = (char*)d_ws;
    bf16*  Whg  = (bf16*)w;                         // 393216
    bf16*  Wlg  = (bf16*)(w + 393216);              // 131072 -> 524288
    bf16*  Wob  = (bf16*)(w + 524288);              // 131072 -> 655360
    f16x2* YZp  = (f16x2*)(w + 655360);             // 8 MiB  -> 9043968
    float* Psum = (float*)(w + 9043968);            // 128 KiB -> 9175040
    float* Ssum = (float*)(w + 9175040);            // 128 KiB -> 9306112
    float* Carry= (float*)(w + 9306112);            // 128 KiB -> 9437184
    float* zpg  = (float*)(w + 9437184);            // 4 KiB zeroed

    hipLaunchKernelGGL(k0_prep,     dim3(1032), dim3(256), 0, stream,
                       in_proj_w, out_proj_w, Whg, Wlg, Wob, zpg);
    hipLaunchKernelGGL(k1_convproj, dim3(256),  dim3(512), 0, stream,
                       x, conv_w, conv_b, in_proj_b, A_log, Whg, Wlg, zpg,
                       YZp, Psum, Ssum);
    hipLaunchKernelGGL(k2_scan2,    dim3(8),    dim3(64),  0, stream, Psum, Ssum, Carry);
    hipLaunchKernelGGL(k3_scan_out, dim3(512),  dim3(512), 0, stream,
                       YZp, Carry, Wob, out_proj_b, out);
}